// Round 11
// baseline (318.899 us; speedup 1.0000x reference)
//
#include <hip/hip_runtime.h>
#include <cmath>

constexpr int NN  = 50000;          // nodes
constexpr int EE  = 800000;         // raw edges
constexpr int E2C = EE + NN;        // edges incl. self loops = 850000
constexpr int DIM = 128;            // input dim to every layer's GEMM

// bucketed counting sort params
constexpr int NBUCK = 256;          // dst buckets
constexpr int BW    = 196;          // bucket width: 196*256 = 50176 >= NN
constexpr int EPT   = 16;           // edges per thread (hist / bin)
constexpr int CH    = 256 * EPT;    // 4096 edges per block
constexpr int NB_B  = (E2C + CH - 1) / CH;  // 208 blocks

using bf16x8 = __attribute__((ext_vector_type(8))) short;
using f32x4  = __attribute__((ext_vector_type(4))) float;

// bf16 helpers (storage bf16, math fp32)
__device__ inline unsigned bf16rne(float f) {
    unsigned u = __builtin_bit_cast(unsigned, f);
    return (u + 0x7fffu + ((u >> 16) & 1u)) >> 16;     // round-nearest-even
}
__device__ inline float bflo(unsigned u) { return __builtin_bit_cast(float, u << 16); }
__device__ inline float bfhi(unsigned u) { return __builtin_bit_cast(float, u & 0xffff0000u); }

// ---------------------------------------------------------------------------
// W[k,c] fp32 -> Wt[c,k] bf16, all three weights in one kernel.
// ---------------------------------------------------------------------------
__global__ __launch_bounds__(256) void cvt_weights(
    const float* __restrict__ W1, const float* __restrict__ W2,
    const float* __restrict__ W3,
    unsigned short* __restrict__ W1t, unsigned short* __restrict__ W2t,
    unsigned short* __restrict__ W3t)
{
    int g = blockIdx.x * 256 + threadIdx.x;
    const float* W; unsigned short* Wt; int cols;
    if (g < 2048)      { W = W1; Wt = W1t; cols = 128; }
    else if (g < 4096) { W = W2; Wt = W2t; cols = 128; g -= 2048; }
    else if (g < 4608) { W = W3; Wt = W3t; cols = 32;  g -= 4096; }
    else return;
    int c  = g / 16;
    int k8 = (g % 16) * 8;
    unsigned up[4];
    #pragma unroll
    for (int j = 0; j < 4; ++j) {
        float a = W[(k8 + 2 * j) * cols + c];
        float b = W[(k8 + 2 * j + 1) * cols + c];
        up[j] = bf16rne(a) | (bf16rne(b) << 16);
    }
    uint4 u; u.x = up[0]; u.y = up[1]; u.z = up[2]; u.w = up[3];
    *(uint4*)(Wt + c * 128 + k8) = u;
}

// ---------------------------------------------------------------------------
// MFMA GEMM: h[N,COLS] (bf16) = in[N,128] @ W (via Wt[c,k] bf16).
// 256 threads = 4 waves; each wave: 16 nodes x COLS. NT = COLS/16 tiles.
// F32IN: input is fp32 (layer 1), converted in-register to the A fragment.
//  A[m=lane&15][k=quad*8+j] ; B[n=lane&15][k=quad*8+j] ; D row=quad*4+r, col=lane&15.
// ---------------------------------------------------------------------------
template<int NT, bool F32IN>
__global__ __launch_bounds__(256) void gemm_mfma(
    const void* __restrict__ inv, const unsigned short* __restrict__ Wt,
    unsigned short* __restrict__ hout)
{
    constexpr int COLS = NT * 16;
    const int lane = threadIdx.x & 63;
    const int wave = threadIdx.x >> 6;
    const int m    = lane & 15;
    const int quad = lane >> 4;
    const int n0   = blockIdx.x * 64 + wave * 16;

    int arow = n0 + m; if (arow >= NN) arow = NN - 1;

    f32x4 acc[NT] = {};
    #pragma unroll
    for (int kq = 0; kq < 4; ++kq) {
        bf16x8 a;
        if constexpr (F32IN) {
            const float* ap = (const float*)inv + (long long)arow * 128 + quad * 8 + kq * 32;
            float4 v0 = *(const float4*)ap;
            float4 v1 = *(const float4*)(ap + 4);
            a[0] = (short)bf16rne(v0.x); a[1] = (short)bf16rne(v0.y);
            a[2] = (short)bf16rne(v0.z); a[3] = (short)bf16rne(v0.w);
            a[4] = (short)bf16rne(v1.x); a[5] = (short)bf16rne(v1.y);
            a[6] = (short)bf16rne(v1.z); a[7] = (short)bf16rne(v1.w);
        } else {
            a = *(const bf16x8*)((const unsigned short*)inv
                    + (long long)arow * 128 + quad * 8 + kq * 32);
        }
        #pragma unroll
        for (int t = 0; t < NT; ++t) {
            bf16x8 b = *(const bf16x8*)(Wt + (t * 16 + m) * 128 + kq * 32 + quad * 8);
            acc[t] = __builtin_amdgcn_mfma_f32_16x16x32_bf16(a, b, acc[t], 0, 0, 0);
        }
    }

    #pragma unroll
    for (int r = 0; r < 4; ++r) {
        int node = n0 + quad * 4 + r;
        if (node < NN) {
            #pragma unroll
            for (int t = 0; t < NT; ++t)
                hout[(long long)node * COLS + t * 16 + m] =
                    (unsigned short)bf16rne(acc[t][r]);
        }
    }
}

// ---------------------------------------------------------------------------
// Per-node attention coefficients from bf16 h: one thread per (node, head).
// ---------------------------------------------------------------------------
template<int NH, int COLS>
__global__ __launch_bounds__(256) void alpha_kernel(
    const unsigned short* __restrict__ h16,
    const float* __restrict__ a_s, const float* __restrict__ a_d,
    float* __restrict__ asrc, float* __restrict__ adst)
{
    int idx = blockIdx.x * 256 + threadIdx.x;
    int node = idx / NH;
    int head = idx % NH;
    if (node >= NN) return;
    const uint4* row = (const uint4*)(h16 + (long long)node * COLS + head * 32);
    float ps = 0.f, pd = 0.f;
    #pragma unroll
    for (int q = 0; q < 4; ++q) {
        uint4 u = row[q];
        unsigned w[4] = {u.x, u.y, u.z, u.w};
        #pragma unroll
        for (int j = 0; j < 4; ++j) {
            float lo = bflo(w[j]), hi = bfhi(w[j]);
            int c = head * 32 + q * 8 + 2 * j;
            ps = fmaf(lo, a_s[c], ps);     ps = fmaf(hi, a_s[c + 1], ps);
            pd = fmaf(lo, a_d[c], pd);     pd = fmaf(hi, a_d[c + 1], pd);
        }
    }
    asrc[node * NH + head] = ps;
    adst[node * NH + head] = pd;
}

// ---------------------------------------------------------------------------
// CSR build. Records packed as  src:16 | dlocal:8 | bucket:8  (N<2^16,
// BW=196<2^8, NBUCK=256). sorted_src stored as ushort.
// ---------------------------------------------------------------------------
__global__ __launch_bounds__(256) void bucket_hist(
    const int* __restrict__ ei, int* __restrict__ bhist)
{
    __shared__ int cnt[NBUCK];
    const int tid = threadIdx.x;
    const long long e0 = (long long)blockIdx.x * CH;
    cnt[tid] = 0;
    __syncthreads();
    #pragma unroll
    for (int j = 0; j < EPT; ++j) {
        long long e = e0 + tid + j * 256;
        if (e < E2C) {
            int dd = (e < EE) ? ei[EE + e] : (int)(e - EE);
            atomicAdd(&cnt[dd / BW], 1);
        }
    }
    __syncthreads();
    if (cnt[tid]) atomicAdd(&bhist[tid], cnt[tid]);
}

__global__ void scan_buckets(const int* __restrict__ bhist,
                             int* __restrict__ bbase, int* __restrict__ bcursor,
                             int* __restrict__ rowptr)
{
    __shared__ int tmp[NBUCK];
    const int tid = threadIdx.x;         // <<<1, 256>>>
    int v = bhist[tid];
    tmp[tid] = v;
    __syncthreads();
    for (int off = 1; off < NBUCK; off <<= 1) {
        int t = (tid >= off) ? tmp[tid - off] : 0;
        __syncthreads();
        tmp[tid] += t;
        __syncthreads();
    }
    int excl = tmp[tid] - v;
    bbase[tid]   = excl;
    bcursor[tid] = excl;
    if (tid == NBUCK - 1) bbase[NBUCK] = tmp[tid];   // == E2C
    if (tid == 0) rowptr[NN] = E2C;
}

__global__ __launch_bounds__(256) void bucket_bin(
    const int* __restrict__ ei, int* __restrict__ bcursor,
    unsigned* __restrict__ pairs)
{
    __shared__ int cnt[NBUCK];
    __shared__ int scanex[NBUCK];
    __shared__ int base[NBUCK];
    __shared__ int cur[NBUCK];
    __shared__ unsigned stage[CH];       // 16 KB

    const int tid = threadIdx.x;
    const long long e0 = (long long)blockIdx.x * CH;
    cnt[tid] = 0;
    __syncthreads();

    unsigned rec[EPT]; int bk[EPT];
    #pragma unroll
    for (int j = 0; j < EPT; ++j) {
        long long e = e0 + tid + j * 256;
        bool valid = e < E2C;
        int ss = 0, dd = 0;
        if (valid) {
            if (e < EE) { ss = ei[e]; dd = ei[EE + e]; }
            else        { ss = dd = (int)(e - EE); }
        }
        int b = dd / BW;
        bk[j]  = valid ? b : -1;
        rec[j] = (unsigned)ss | ((unsigned)(dd - b * BW) << 16) | ((unsigned)b << 24);
        if (valid) atomicAdd(&cnt[b], 1);
    }
    __syncthreads();

    const int myc = cnt[tid];
    scanex[tid] = myc;
    __syncthreads();
    for (int off = 1; off < NBUCK; off <<= 1) {
        int t = (tid >= off) ? scanex[tid - off] : 0;
        __syncthreads();
        scanex[tid] += t;
        __syncthreads();
    }
    int excl = scanex[tid] - myc;
    __syncthreads();
    scanex[tid] = excl;
    cur[tid]    = excl;
    base[tid]   = atomicAdd(&bcursor[tid], myc);   // reserve global chunk
    __syncthreads();

    #pragma unroll
    for (int j = 0; j < EPT; ++j) {
        if (bk[j] >= 0) {
            int p = atomicAdd(&cur[bk[j]], 1);
            stage[p] = rec[j];
        }
    }
    __syncthreads();

    const int total = (e0 + CH <= E2C) ? CH : (int)(E2C - e0);
    for (int j = tid; j < total; j += 256) {
        unsigned p = stage[j];
        int b = (int)(p >> 24);
        pairs[base[b] + (j - scanex[b])] = p;
    }
}

__global__ __launch_bounds__(256) void bucket_sort(
    const int* __restrict__ bbase, const unsigned* __restrict__ pairs,
    int* __restrict__ rowptr, unsigned short* __restrict__ sorted_src)
{
    __shared__ int deg[256];
    __shared__ int cur[256];
    const int b  = blockIdx.x;
    const int n0 = b * BW;
    const int n1 = (n0 + BW < NN) ? n0 + BW : NN;
    const int nloc = n1 - n0;
    const int tid = threadIdx.x;
    const int beg = bbase[b], end = bbase[b + 1];

    deg[tid] = 0;
    __syncthreads();
    for (int i = beg + tid; i < end; i += 256)
        atomicAdd(&deg[(pairs[i] >> 16) & 0xff], 1);
    __syncthreads();

    int v = deg[tid];
    cur[tid] = v;
    __syncthreads();
    for (int off = 1; off < 256; off <<= 1) {
        int t = (tid >= off) ? cur[tid - off] : 0;
        __syncthreads();
        cur[tid] += t;
        __syncthreads();
    }
    int excl = cur[tid] - v;
    __syncthreads();
    cur[tid] = beg + excl;
    if (tid < nloc) rowptr[n0 + tid] = beg + excl;
    __syncthreads();

    for (int i = beg + tid; i < end; i += 256) {
        unsigned p = pairs[i];
        int pos = atomicAdd(&cur[(p >> 16) & 0xff], 1);
        sorted_src[pos] = (unsigned short)(p & 0xffff);
    }
}

// ---------------------------------------------------------------------------
// CSR gather aggregation over bf16 h (consecutive-d): 8 channels/lane
// (uint4 = 16B), 8-edge batching (24 loads in flight), COLS/8 lanes/node.
// ---------------------------------------------------------------------------
template<int COLS, int NH, bool DO_ELU, bool OUTBF>
__global__ __launch_bounds__(256) void aggr_csr(
    const int* __restrict__ rowptr, const unsigned short* __restrict__ sorted_src,
    const unsigned short* __restrict__ hin,
    const float* __restrict__ asrc, const float* __restrict__ adst,
    const float* __restrict__ bias, void* __restrict__ outv)
{
    constexpr int TPN = COLS / 8;             // lanes per node: 16 or 4
    constexpr int USTR = COLS / 2;            // uints per h row
    int t = blockIdx.x * 256 + threadIdx.x;
    int d = t / TPN;
    int lc = t % TPN;                         // owns channels 8*lc .. 8*lc+7
    if (d >= NN) return;
    const int cc = lc * 8;
    const int head = cc / 32;                 // 0..NH-1
    const float ad = adst[d * NH + head];
    const int beg = rowptr[d], end = rowptr[d + 1];
    const uint* hp = (const uint*)hin;

    float num[8] = {};
    float den = 0.f;

    auto accum = [&](float w, uint4 H) {
        den += w;
        num[0] = fmaf(w, bflo(H.x), num[0]); num[1] = fmaf(w, bfhi(H.x), num[1]);
        num[2] = fmaf(w, bflo(H.y), num[2]); num[3] = fmaf(w, bfhi(H.y), num[3]);
        num[4] = fmaf(w, bflo(H.z), num[4]); num[5] = fmaf(w, bfhi(H.z), num[5]);
        num[6] = fmaf(w, bflo(H.w), num[6]); num[7] = fmaf(w, bfhi(H.w), num[7]);
    };

    int i = beg;
    for (; i + 8 <= end; i += 8) {
        int   s[8];
        float a[8];
        uint4 Hv[8];
        #pragma unroll
        for (int j = 0; j < 8; ++j) s[j] = sorted_src[i + j];
        #pragma unroll
        for (int j = 0; j < 8; ++j) a[j] = asrc[s[j] * NH + head];
        #pragma unroll
        for (int j = 0; j < 8; ++j)
            Hv[j] = *(const uint4*)&hp[(long long)s[j] * USTR + cc / 2];
        #pragma unroll
        for (int j = 0; j < 8; ++j) {
            float l = a[j] + ad; l = l > 0.f ? l : 0.2f * l;
            accum(__builtin_expf(l), Hv[j]);
        }
    }
    for (; i + 4 <= end; i += 4) {
        int   s[4];
        float a[4];
        uint4 Hv[4];
        #pragma unroll
        for (int j = 0; j < 4; ++j) s[j] = sorted_src[i + j];
        #pragma unroll
        for (int j = 0; j < 4; ++j) a[j] = asrc[s[j] * NH + head];
        #pragma unroll
        for (int j = 0; j < 4; ++j)
            Hv[j] = *(const uint4*)&hp[(long long)s[j] * USTR + cc / 2];
        #pragma unroll
        for (int j = 0; j < 4; ++j) {
            float l = a[j] + ad; l = l > 0.f ? l : 0.2f * l;
            accum(__builtin_expf(l), Hv[j]);
        }
    }
    for (; i < end; ++i) {
        int s = sorted_src[i];
        float a = asrc[s * NH + head];
        uint4 H = *(const uint4*)&hp[(long long)s * USTR + cc / 2];
        float l = a + ad; l = l > 0.f ? l : 0.2f * l;
        accum(__builtin_expf(l), H);
    }

    float inv = 1.f / (den + 1e-16f);
    float v[8];
    #pragma unroll
    for (int j = 0; j < 8; ++j) {
        v[j] = num[j] * inv + bias[cc + j];
        if (DO_ELU) v[j] = v[j] > 0.f ? v[j] : expm1f(v[j]);
    }
    if constexpr (OUTBF) {
        uint4 u;
        u.x = bf16rne(v[0]) | (bf16rne(v[1]) << 16);
        u.y = bf16rne(v[2]) | (bf16rne(v[3]) << 16);
        u.z = bf16rne(v[4]) | (bf16rne(v[5]) << 16);
        u.w = bf16rne(v[6]) | (bf16rne(v[7]) << 16);
        *(uint4*)((unsigned short*)outv + (long long)d * COLS + cc) = u;
    } else {
        float4 o0 = {v[0], v[1], v[2], v[3]};
        float4 o1 = {v[4], v[5], v[6], v[7]};
        float* out = (float*)outv;
        *(float4*)&out[(long long)d * COLS + cc]     = o0;
        *(float4*)&out[(long long)d * COLS + cc + 4] = o1;
    }
}

// ---------------------------------------------------------------------------
extern "C" void kernel_launch(void* const* d_in, const int* in_sizes, int n_in,
                              void* d_out, int out_size, void* d_ws, size_t ws_size,
                              hipStream_t stream)
{
    const float* x   = (const float*)d_in[0];
    const int*   ei  = (const int*)  d_in[1];
    const float* W1  = (const float*)d_in[2];
    const float* as1 = (const float*)d_in[3];
    const float* ad1 = (const float*)d_in[4];
    const float* b1  = (const float*)d_in[5];
    const float* W2  = (const float*)d_in[6];
    const float* as2 = (const float*)d_in[7];
    const float* ad2 = (const float*)d_in[8];
    const float* b2  = (const float*)d_in[9];
    const float* W3  = (const float*)d_in[10];
    const float* as3 = (const float*)d_in[11];
    const float* ad3 = (const float*)d_in[12];
    const float* b3  = (const float*)d_in[13];
    float* out = (float*)d_out;

    // workspace layout (16B-aligned bf16 buffers first)
    unsigned short* H16 = (unsigned short*)d_ws;          // N*128 bf16 (h)
    unsigned short* O16 = H16 + (size_t)NN * 128;         // N*128 bf16 (aggr out 1 / gemm2 in)
    unsigned short* P16 = O16 + (size_t)NN * 128;         // N*128 bf16 (aggr out 2 / gemm3 in)
    unsigned short* W1t = P16 + (size_t)NN * 128;         // 128*128 bf16
    unsigned short* W2t = W1t + 128 * 128;
    unsigned short* W3t = W2t + 128 * 128;                // 32*128
    float* ASRC = (float*)(W3t + 32 * 128);               // N*4
    float* ADST = ASRC + (size_t)NN * 4;                  // N*4
    int* rowptr = (int*)(ADST + (size_t)NN * 4);          // NN+1
    unsigned short* sorted = (unsigned short*)(rowptr + NN + 1);   // E2C u16
    int* bhist  = (int*)(sorted + E2C + (E2C & 1));       // NBUCK
    int* bbase  = bhist + NBUCK;                          // NBUCK+1
    int* bcursor= bbase + NBUCK + 1;                      // NBUCK
    size_t off = ((size_t)(bcursor + NBUCK) - (size_t)d_ws + 15) & ~(size_t)15;
    unsigned* pairs = (unsigned*)((char*)d_ws + off);     // E2C u32 (3.4 MB)

    const int gCvtW    = (4608 + 255) / 256;             // 18
    const int gGemm    = (NN + 63) / 64;                 // 782
    const int gAlpha4  = (NN * 4 + 255) / 256;           // 782
    const int gAlpha1  = (NN + 255) / 256;               // 196
    const int gAggr128 = (NN * 16 + 255) / 256;          // 3125
    const int gAggr32  = (NN * 4 + 255) / 256;           // 782

    // ---- CSR build (reused by all layers) + weight conversion ----
    hipMemsetAsync(bhist, 0, NBUCK * sizeof(int), stream);
    bucket_hist<<<NB_B, 256, 0, stream>>>(ei, bhist);
    scan_buckets<<<1, NBUCK, 0, stream>>>(bhist, bbase, bcursor, rowptr);
    bucket_bin<<<NB_B, 256, 0, stream>>>(ei, bcursor, pairs);
    bucket_sort<<<NBUCK, 256, 0, stream>>>(bbase, pairs, rowptr, sorted);
    cvt_weights<<<gCvtW, 256, 0, stream>>>(W1, W2, W3, W1t, W2t, W3t);

    // ---- layer 1 (128 -> 4x32 concat, ELU); fp32 x read directly ----
    gemm_mfma<8, true><<<gGemm, 256, 0, stream>>>(x, W1t, H16);
    alpha_kernel<4, 128><<<gAlpha4, 256, 0, stream>>>(H16, as1, ad1, ASRC, ADST);
    aggr_csr<128, 4, true, true><<<gAggr128, 256, 0, stream>>>(
        rowptr, sorted, H16, ASRC, ADST, b1, O16);

    // ---- layer 2 (128 -> 4x32 concat, ELU) ----
    gemm_mfma<8, false><<<gGemm, 256, 0, stream>>>(O16, W2t, H16);
    alpha_kernel<4, 128><<<gAlpha4, 256, 0, stream>>>(H16, as2, ad2, ASRC, ADST);
    aggr_csr<128, 4, true, true><<<gAggr128, 256, 0, stream>>>(
        rowptr, sorted, H16, ASRC, ADST, b2, P16);

    // ---- layer 3 (128 -> 32, 1 head, no concat) ----
    gemm_mfma<2, false><<<gGemm, 256, 0, stream>>>(P16, W3t, H16);   // H16 = N*32
    alpha_kernel<1, 32><<<gAlpha1, 256, 0, stream>>>(H16, as3, ad3, ASRC, ADST);
    aggr_csr<32, 1, false, false><<<gAggr32, 256, 0, stream>>>(
        rowptr, sorted, H16, ASRC, ADST, b3, out);
}

// Round 12
// 298.955 us; speedup vs baseline: 1.0667x; 1.0667x over previous
//
#include <hip/hip_runtime.h>
#include <cmath>

constexpr int NN  = 50000;          // nodes
constexpr int EE  = 800000;         // raw edges
constexpr int E2C = EE + NN;        // edges incl. self loops = 850000
constexpr int DIM = 128;            // input dim to every layer's GEMM

// bucketed counting sort params
constexpr int NBUCK = 256;          // dst buckets
constexpr int BW    = 196;          // bucket width: 196*256 = 50176 >= NN
constexpr int EPT   = 16;           // edges per thread (hist / bin)
constexpr int CH    = 256 * EPT;    // 4096 edges per block
constexpr int NB_B  = (E2C + CH - 1) / CH;  // 208 blocks

using bf16x8 = __attribute__((ext_vector_type(8))) short;
using f32x4  = __attribute__((ext_vector_type(4))) float;

// bf16 helpers (storage bf16, math fp32)
__device__ inline unsigned bf16rne(float f) {
    unsigned u = __builtin_bit_cast(unsigned, f);
    return (u + 0x7fffu + ((u >> 16) & 1u)) >> 16;     // round-nearest-even
}
__device__ inline float bflo(unsigned u) { return __builtin_bit_cast(float, u << 16); }
__device__ inline float bfhi(unsigned u) { return __builtin_bit_cast(float, u & 0xffff0000u); }

// ---------------------------------------------------------------------------
// W[k,c] fp32 -> Wt[c,k] bf16, all three weights in one kernel.
// ---------------------------------------------------------------------------
__global__ __launch_bounds__(256) void cvt_weights(
    const float* __restrict__ W1, const float* __restrict__ W2,
    const float* __restrict__ W3,
    unsigned short* __restrict__ W1t, unsigned short* __restrict__ W2t,
    unsigned short* __restrict__ W3t)
{
    int g = blockIdx.x * 256 + threadIdx.x;
    const float* W; unsigned short* Wt; int cols;
    if (g < 2048)      { W = W1; Wt = W1t; cols = 128; }
    else if (g < 4096) { W = W2; Wt = W2t; cols = 128; g -= 2048; }
    else if (g < 4608) { W = W3; Wt = W3t; cols = 32;  g -= 4096; }
    else return;
    int c  = g / 16;
    int k8 = (g % 16) * 8;
    unsigned up[4];
    #pragma unroll
    for (int j = 0; j < 4; ++j) {
        float a = W[(k8 + 2 * j) * cols + c];
        float b = W[(k8 + 2 * j + 1) * cols + c];
        up[j] = bf16rne(a) | (bf16rne(b) << 16);
    }
    uint4 u; u.x = up[0]; u.y = up[1]; u.z = up[2]; u.w = up[3];
    *(uint4*)(Wt + c * 128 + k8) = u;
}

// ---------------------------------------------------------------------------
// MFMA GEMM + fused attention coefficients.
// h[N,COLS] (bf16) = in[N,128] @ W (Wt[c,k] bf16). 4 waves, 16 nodes/wave.
// NT = COLS/16 tiles; NH heads (head = NT/NH adjacent tiles = 32 cols).
// A[m=lane&15][k=quad*8+j]; B[n=lane&15][k=quad*8+j]; D row=quad*4+r, col=lane&15.
// Epilogue: per-head dot(h, a_s/a_d) via in-register partials + 16-lane
// shuffle reduce. Also writes the asrc sentinel row (node NN) = -1e30.
// ---------------------------------------------------------------------------
template<int NT, int NH, bool F32IN>
__global__ __launch_bounds__(256) void gemm_mfma(
    const void* __restrict__ inv, const unsigned short* __restrict__ Wt,
    const float* __restrict__ a_s, const float* __restrict__ a_d,
    unsigned short* __restrict__ hout, float* __restrict__ asrc,
    float* __restrict__ adst)
{
    constexpr int COLS = NT * 16;
    constexpr int TPH  = NT / NH;        // tiles per head (2)
    const int lane = threadIdx.x & 63;
    const int wave = threadIdx.x >> 6;
    const int m    = lane & 15;
    const int quad = lane >> 4;
    const int n0   = blockIdx.x * 64 + wave * 16;

    int arow = n0 + m; if (arow >= NN) arow = NN - 1;

    f32x4 acc[NT] = {};
    #pragma unroll
    for (int kq = 0; kq < 4; ++kq) {
        bf16x8 a;
        if constexpr (F32IN) {
            const float* ap = (const float*)inv + (long long)arow * 128 + quad * 8 + kq * 32;
            float4 v0 = *(const float4*)ap;
            float4 v1 = *(const float4*)(ap + 4);
            a[0] = (short)bf16rne(v0.x); a[1] = (short)bf16rne(v0.y);
            a[2] = (short)bf16rne(v0.z); a[3] = (short)bf16rne(v0.w);
            a[4] = (short)bf16rne(v1.x); a[5] = (short)bf16rne(v1.y);
            a[6] = (short)bf16rne(v1.z); a[7] = (short)bf16rne(v1.w);
        } else {
            a = *(const bf16x8*)((const unsigned short*)inv
                    + (long long)arow * 128 + quad * 8 + kq * 32);
        }
        #pragma unroll
        for (int t = 0; t < NT; ++t) {
            bf16x8 b = *(const bf16x8*)(Wt + (t * 16 + m) * 128 + kq * 32 + quad * 8);
            acc[t] = __builtin_amdgcn_mfma_f32_16x16x32_bf16(a, b, acc[t], 0, 0, 0);
        }
    }

    // ---- h store ----
    #pragma unroll
    for (int r = 0; r < 4; ++r) {
        int node = n0 + quad * 4 + r;
        if (node < NN) {
            #pragma unroll
            for (int t = 0; t < NT; ++t)
                hout[(long long)node * COLS + t * 16 + m] =
                    (unsigned short)bf16rne(acc[t][r]);
        }
    }

    // ---- fused alpha: per-head dots + 16-lane reduction ----
    float asv[NT], adv[NT];
    #pragma unroll
    for (int t = 0; t < NT; ++t) { asv[t] = a_s[t * 16 + m]; adv[t] = a_d[t * 16 + m]; }

    #pragma unroll
    for (int r = 0; r < 4; ++r) {
        const int node = n0 + quad * 4 + r;
        #pragma unroll
        for (int hh = 0; hh < NH; ++hh) {
            float ps = 0.f, pd = 0.f;
            #pragma unroll
            for (int q = 0; q < TPH; ++q) {
                int t = hh * TPH + q;
                ps = fmaf(acc[t][r], asv[t], ps);
                pd = fmaf(acc[t][r], adv[t], pd);
            }
            #pragma unroll
            for (int off = 8; off > 0; off >>= 1) {
                ps += __shfl_down(ps, off, 16);
                pd += __shfl_down(pd, off, 16);
            }
            if (m == 0 && node < NN) {
                asrc[node * NH + hh] = ps;
                adst[node * NH + hh] = pd;
            }
        }
    }

    // sentinel row for masked-tail aggregation: exp(-1e30 + ...) == 0
    if (blockIdx.x == 0 && threadIdx.x == 0) {
        #pragma unroll
        for (int hh = 0; hh < NH; ++hh) asrc[NN * NH + hh] = -1e30f;
    }
}

// ---------------------------------------------------------------------------
// CSR build. Records packed as  src:16 | dlocal:8 | bucket:8.
// ---------------------------------------------------------------------------
__global__ __launch_bounds__(256) void bucket_hist(
    const int* __restrict__ ei, int* __restrict__ bhist)
{
    __shared__ int cnt[NBUCK];
    const int tid = threadIdx.x;
    const long long e0 = (long long)blockIdx.x * CH;
    cnt[tid] = 0;
    __syncthreads();
    #pragma unroll
    for (int j = 0; j < EPT; ++j) {
        long long e = e0 + tid + j * 256;
        if (e < E2C) {
            int dd = (e < EE) ? ei[EE + e] : (int)(e - EE);
            atomicAdd(&cnt[dd / BW], 1);
        }
    }
    __syncthreads();
    if (cnt[tid]) atomicAdd(&bhist[tid], cnt[tid]);
}

__global__ void scan_buckets(const int* __restrict__ bhist,
                             int* __restrict__ bbase, int* __restrict__ bcursor,
                             int* __restrict__ rowptr)
{
    __shared__ int tmp[NBUCK];
    const int tid = threadIdx.x;         // <<<1, 256>>>
    int v = bhist[tid];
    tmp[tid] = v;
    __syncthreads();
    for (int off = 1; off < NBUCK; off <<= 1) {
        int t = (tid >= off) ? tmp[tid - off] : 0;
        __syncthreads();
        tmp[tid] += t;
        __syncthreads();
    }
    int excl = tmp[tid] - v;
    bbase[tid]   = excl;
    bcursor[tid] = excl;
    if (tid == NBUCK - 1) bbase[NBUCK] = tmp[tid];   // == E2C
    if (tid == 0) rowptr[NN] = E2C;
}

__global__ __launch_bounds__(256) void bucket_bin(
    const int* __restrict__ ei, int* __restrict__ bcursor,
    unsigned* __restrict__ pairs)
{
    __shared__ int cnt[NBUCK];
    __shared__ int scanex[NBUCK];
    __shared__ int base[NBUCK];
    __shared__ int cur[NBUCK];
    __shared__ unsigned stage[CH];       // 16 KB

    const int tid = threadIdx.x;
    const long long e0 = (long long)blockIdx.x * CH;
    cnt[tid] = 0;
    __syncthreads();

    unsigned rec[EPT]; int bk[EPT];
    #pragma unroll
    for (int j = 0; j < EPT; ++j) {
        long long e = e0 + tid + j * 256;
        bool valid = e < E2C;
        int ss = 0, dd = 0;
        if (valid) {
            if (e < EE) { ss = ei[e]; dd = ei[EE + e]; }
            else        { ss = dd = (int)(e - EE); }
        }
        int b = dd / BW;
        bk[j]  = valid ? b : -1;
        rec[j] = (unsigned)ss | ((unsigned)(dd - b * BW) << 16) | ((unsigned)b << 24);
        if (valid) atomicAdd(&cnt[b], 1);
    }
    __syncthreads();

    const int myc = cnt[tid];
    scanex[tid] = myc;
    __syncthreads();
    for (int off = 1; off < NBUCK; off <<= 1) {
        int t = (tid >= off) ? scanex[tid - off] : 0;
        __syncthreads();
        scanex[tid] += t;
        __syncthreads();
    }
    int excl = scanex[tid] - myc;
    __syncthreads();
    scanex[tid] = excl;
    cur[tid]    = excl;
    base[tid]   = atomicAdd(&bcursor[tid], myc);   // reserve global chunk
    __syncthreads();

    #pragma unroll
    for (int j = 0; j < EPT; ++j) {
        if (bk[j] >= 0) {
            int p = atomicAdd(&cur[bk[j]], 1);
            stage[p] = rec[j];
        }
    }
    __syncthreads();

    const int total = (e0 + CH <= E2C) ? CH : (int)(E2C - e0);
    for (int j = tid; j < total; j += 256) {
        unsigned p = stage[j];
        int b = (int)(p >> 24);
        pairs[base[b] + (j - scanex[b])] = p;
    }
}

__global__ __launch_bounds__(256) void bucket_sort(
    const int* __restrict__ bbase, const unsigned* __restrict__ pairs,
    int* __restrict__ rowptr, unsigned short* __restrict__ sorted_src)
{
    __shared__ int deg[256];
    __shared__ int cur[256];
    const int b  = blockIdx.x;
    const int n0 = b * BW;
    const int n1 = (n0 + BW < NN) ? n0 + BW : NN;
    const int nloc = n1 - n0;
    const int tid = threadIdx.x;
    const int beg = bbase[b], end = bbase[b + 1];

    deg[tid] = 0;
    __syncthreads();
    for (int i = beg + tid; i < end; i += 256)
        atomicAdd(&deg[(pairs[i] >> 16) & 0xff], 1);
    __syncthreads();

    int v = deg[tid];
    cur[tid] = v;
    __syncthreads();
    for (int off = 1; off < 256; off <<= 1) {
        int t = (tid >= off) ? cur[tid - off] : 0;
        __syncthreads();
        cur[tid] += t;
        __syncthreads();
    }
    int excl = cur[tid] - v;
    __syncthreads();
    cur[tid] = beg + excl;
    if (tid < nloc) rowptr[n0 + tid] = beg + excl;
    __syncthreads();

    for (int i = beg + tid; i < end; i += 256) {
        unsigned p = pairs[i];
        int pos = atomicAdd(&cur[(p >> 16) & 0xff], 1);
        sorted_src[pos] = (unsigned short)(p & 0xffff);
    }
}

// ---------------------------------------------------------------------------
// CSR gather aggregation over bf16 h (consecutive-d, 4-deep masked batches,
// no tail loops): out-of-range slots map to sentinel node NN whose
// asrc = -1e30 => exp = 0 contribution. 8 channels/lane, COLS/8 lanes/node.
// ---------------------------------------------------------------------------
template<int COLS, int NH, bool DO_ELU, bool OUTBF>
__global__ __launch_bounds__(256) void aggr_csr(
    const int* __restrict__ rowptr, const unsigned short* __restrict__ sorted_src,
    const unsigned short* __restrict__ hin,
    const float* __restrict__ asrc, const float* __restrict__ adst,
    const float* __restrict__ bias, void* __restrict__ outv)
{
    constexpr int TPN = COLS / 8;             // lanes per node: 16 or 4
    constexpr int USTR = COLS / 2;            // uints per h row
    int t = blockIdx.x * 256 + threadIdx.x;
    int d = t / TPN;
    int lc = t % TPN;                         // owns channels 8*lc .. 8*lc+7
    if (d >= NN) return;
    const int cc = lc * 8;
    const int head = cc / 32;                 // 0..NH-1
    const float ad = adst[d * NH + head];
    const int beg = rowptr[d], end = rowptr[d + 1];
    const uint* hp = (const uint*)hin + cc / 2;

    float num[8] = {};
    float den = 0.f;

    for (int i = beg; i < end; i += 4) {
        int   s[4];
        float a[4];
        uint4 Hv[4];
        #pragma unroll
        for (int j = 0; j < 4; ++j) {
            int sv = sorted_src[i + j];               // +3 over-read: slack alloc
            s[j] = (i + j < end) ? sv : NN;           // sentinel
        }
        #pragma unroll
        for (int j = 0; j < 4; ++j) a[j] = asrc[s[j] * NH + head];
        #pragma unroll
        for (int j = 0; j < 4; ++j)
            Hv[j] = *(const uint4*)&hp[(long long)s[j] * USTR];
        #pragma unroll
        for (int j = 0; j < 4; ++j) {
            float l = a[j] + ad; l = l > 0.f ? l : 0.2f * l;
            float w = __builtin_expf(l);
            den += w;
            num[0] = fmaf(w, bflo(Hv[j].x), num[0]); num[1] = fmaf(w, bfhi(Hv[j].x), num[1]);
            num[2] = fmaf(w, bflo(Hv[j].y), num[2]); num[3] = fmaf(w, bfhi(Hv[j].y), num[3]);
            num[4] = fmaf(w, bflo(Hv[j].z), num[4]); num[5] = fmaf(w, bfhi(Hv[j].z), num[5]);
            num[6] = fmaf(w, bflo(Hv[j].w), num[6]); num[7] = fmaf(w, bfhi(Hv[j].w), num[7]);
        }
    }

    float inv = 1.f / (den + 1e-16f);
    float v[8];
    #pragma unroll
    for (int j = 0; j < 8; ++j) {
        v[j] = num[j] * inv + bias[cc + j];
        if (DO_ELU) v[j] = v[j] > 0.f ? v[j] : expm1f(v[j]);
    }
    if constexpr (OUTBF) {
        uint4 u;
        u.x = bf16rne(v[0]) | (bf16rne(v[1]) << 16);
        u.y = bf16rne(v[2]) | (bf16rne(v[3]) << 16);
        u.z = bf16rne(v[4]) | (bf16rne(v[5]) << 16);
        u.w = bf16rne(v[6]) | (bf16rne(v[7]) << 16);
        *(uint4*)((unsigned short*)outv + (long long)d * COLS + cc) = u;
    } else {
        float4 o0 = {v[0], v[1], v[2], v[3]};
        float4 o1 = {v[4], v[5], v[6], v[7]};
        float* out = (float*)outv;
        *(float4*)&out[(long long)d * COLS + cc]     = o0;
        *(float4*)&out[(long long)d * COLS + cc + 4] = o1;
    }
}

// ---------------------------------------------------------------------------
extern "C" void kernel_launch(void* const* d_in, const int* in_sizes, int n_in,
                              void* d_out, int out_size, void* d_ws, size_t ws_size,
                              hipStream_t stream)
{
    const float* x   = (const float*)d_in[0];
    const int*   ei  = (const int*)  d_in[1];
    const float* W1  = (const float*)d_in[2];
    const float* as1 = (const float*)d_in[3];
    const float* ad1 = (const float*)d_in[4];
    const float* b1  = (const float*)d_in[5];
    const float* W2  = (const float*)d_in[6];
    const float* as2 = (const float*)d_in[7];
    const float* ad2 = (const float*)d_in[8];
    const float* b2  = (const float*)d_in[9];
    const float* W3  = (const float*)d_in[10];
    const float* as3 = (const float*)d_in[11];
    const float* ad3 = (const float*)d_in[12];
    const float* b3  = (const float*)d_in[13];
    float* out = (float*)d_out;

    // workspace layout (16B-aligned bf16 buffers first). h buffers have an
    // extra sentinel row (node NN).
    unsigned short* H16 = (unsigned short*)d_ws;          // (N+1)*128 bf16
    unsigned short* O16 = H16 + (size_t)(NN + 1) * 128;   // N*128 bf16
    unsigned short* P16 = O16 + (size_t)NN * 128;         // N*128 bf16
    unsigned short* W1t = P16 + (size_t)NN * 128;         // 128*128 bf16
    unsigned short* W2t = W1t + 128 * 128;
    unsigned short* W3t = W2t + 128 * 128;                // 32*128
    float* ASRC = (float*)(W3t + 32 * 128);               // (N+1)*4
    float* ADST = ASRC + (size_t)(NN + 1) * 4;            // N*4
    int* rowptr = (int*)(ADST + (size_t)NN * 4);          // NN+1
    unsigned short* sorted = (unsigned short*)(rowptr + NN + 1);   // E2C+8 u16
    int* bhist  = (int*)(sorted + E2C + 8);               // NBUCK
    int* bbase  = bhist + NBUCK;                          // NBUCK+1
    int* bcursor= bbase + NBUCK + 1;                      // NBUCK
    size_t off = ((size_t)(bcursor + NBUCK) - (size_t)d_ws + 15) & ~(size_t)15;
    unsigned* pairs = (unsigned*)((char*)d_ws + off);     // E2C u32 (3.4 MB)

    const int gCvtW    = (4608 + 255) / 256;             // 18
    const int gGemm    = (NN + 63) / 64;                 // 782
    const int gAggr128 = (NN * 16 + 255) / 256;          // 3125
    const int gAggr32  = (NN * 4 + 255) / 256;           // 782

    // ---- CSR build (reused by all layers) + weight conversion ----
    hipMemsetAsync(bhist, 0, NBUCK * sizeof(int), stream);
    bucket_hist<<<NB_B, 256, 0, stream>>>(ei, bhist);
    scan_buckets<<<1, NBUCK, 0, stream>>>(bhist, bbase, bcursor, rowptr);
    bucket_bin<<<NB_B, 256, 0, stream>>>(ei, bcursor, pairs);
    bucket_sort<<<NBUCK, 256, 0, stream>>>(bbase, pairs, rowptr, sorted);
    cvt_weights<<<gCvtW, 256, 0, stream>>>(W1, W2, W3, W1t, W2t, W3t);

    // ---- layer 1 (128 -> 4x32 concat, ELU); fp32 x read directly ----
    gemm_mfma<8, 4, true><<<gGemm, 256, 0, stream>>>(x, W1t, as1, ad1, H16, ASRC, ADST);
    aggr_csr<128, 4, true, true><<<gAggr128, 256, 0, stream>>>(
        rowptr, sorted, H16, ASRC, ADST, b1, O16);

    // ---- layer 2 (128 -> 4x32 concat, ELU) ----
    gemm_mfma<8, 4, false><<<gGemm, 256, 0, stream>>>(O16, W2t, as2, ad2, H16, ASRC, ADST);
    aggr_csr<128, 4, true, true><<<gAggr128, 256, 0, stream>>>(
        rowptr, sorted, H16, ASRC, ADST, b2, P16);

    // ---- layer 3 (128 -> 32, 1 head, no concat) ----
    gemm_mfma<2, 1, false><<<gGemm, 256, 0, stream>>>(P16, W3t, as3, ad3, H16, ASRC, ADST);
    aggr_csr<32, 1, false, false><<<gAggr32, 256, 0, stream>>>(
        rowptr, sorted, H16, ASRC, ADST, b3, out);
}

// Round 13
// 291.674 us; speedup vs baseline: 1.0933x; 1.0250x over previous
//
#include <hip/hip_runtime.h>
#include <cmath>

constexpr int NN  = 50000;          // nodes
constexpr int EE  = 800000;         // raw edges
constexpr int E2C = EE + NN;        // edges incl. self loops = 850000
constexpr int DIM = 128;            // input dim to every layer's GEMM

// bucketed counting sort params
constexpr int NBUCK = 256;          // dst buckets
constexpr int BW    = 196;          // bucket width: 196*256 = 50176 >= NN
constexpr int EPT   = 16;           // edges per thread (bin)
constexpr int CH    = 256 * EPT;    // 4096 edges per block
constexpr int NB_B  = (E2C + CH - 1) / CH;  // 208 blocks
constexpr int CAP   = 4096;         // per-bucket segment capacity (mean 3320, +13 sigma)

using bf16x8 = __attribute__((ext_vector_type(8))) short;
using f32x4  = __attribute__((ext_vector_type(4))) float;

// bf16 helpers (storage bf16, math fp32)
__device__ inline unsigned bf16rne(float f) {
    unsigned u = __builtin_bit_cast(unsigned, f);
    return (u + 0x7fffu + ((u >> 16) & 1u)) >> 16;     // round-nearest-even
}
__device__ inline float bflo(unsigned u) { return __builtin_bit_cast(float, u << 16); }
__device__ inline float bfhi(unsigned u) { return __builtin_bit_cast(float, u & 0xffff0000u); }

// ---------------------------------------------------------------------------
// W[k,c] fp32 -> Wt[c,k] bf16, all three weights in one kernel.
// ---------------------------------------------------------------------------
__global__ __launch_bounds__(256) void cvt_weights(
    const float* __restrict__ W1, const float* __restrict__ W2,
    const float* __restrict__ W3,
    unsigned short* __restrict__ W1t, unsigned short* __restrict__ W2t,
    unsigned short* __restrict__ W3t)
{
    int g = blockIdx.x * 256 + threadIdx.x;
    const float* W; unsigned short* Wt; int cols;
    if (g < 2048)      { W = W1; Wt = W1t; cols = 128; }
    else if (g < 4096) { W = W2; Wt = W2t; cols = 128; g -= 2048; }
    else if (g < 4608) { W = W3; Wt = W3t; cols = 32;  g -= 4096; }
    else return;
    int c  = g / 16;
    int k8 = (g % 16) * 8;
    unsigned up[4];
    #pragma unroll
    for (int j = 0; j < 4; ++j) {
        float a = W[(k8 + 2 * j) * cols + c];
        float b = W[(k8 + 2 * j + 1) * cols + c];
        up[j] = bf16rne(a) | (bf16rne(b) << 16);
    }
    uint4 u; u.x = up[0]; u.y = up[1]; u.z = up[2]; u.w = up[3];
    *(uint4*)(Wt + c * 128 + k8) = u;
}

// ---------------------------------------------------------------------------
// MFMA GEMM + fused attention coefficients (round-12, unchanged).
// ---------------------------------------------------------------------------
template<int NT, int NH, bool F32IN>
__global__ __launch_bounds__(256) void gemm_mfma(
    const void* __restrict__ inv, const unsigned short* __restrict__ Wt,
    const float* __restrict__ a_s, const float* __restrict__ a_d,
    unsigned short* __restrict__ hout, float* __restrict__ asrc,
    float* __restrict__ adst)
{
    constexpr int COLS = NT * 16;
    constexpr int TPH  = NT / NH;        // tiles per head (2)
    const int lane = threadIdx.x & 63;
    const int wave = threadIdx.x >> 6;
    const int m    = lane & 15;
    const int quad = lane >> 4;
    const int n0   = blockIdx.x * 64 + wave * 16;

    int arow = n0 + m; if (arow >= NN) arow = NN - 1;

    f32x4 acc[NT] = {};
    #pragma unroll
    for (int kq = 0; kq < 4; ++kq) {
        bf16x8 a;
        if constexpr (F32IN) {
            const float* ap = (const float*)inv + (long long)arow * 128 + quad * 8 + kq * 32;
            float4 v0 = *(const float4*)ap;
            float4 v1 = *(const float4*)(ap + 4);
            a[0] = (short)bf16rne(v0.x); a[1] = (short)bf16rne(v0.y);
            a[2] = (short)bf16rne(v0.z); a[3] = (short)bf16rne(v0.w);
            a[4] = (short)bf16rne(v1.x); a[5] = (short)bf16rne(v1.y);
            a[6] = (short)bf16rne(v1.z); a[7] = (short)bf16rne(v1.w);
        } else {
            a = *(const bf16x8*)((const unsigned short*)inv
                    + (long long)arow * 128 + quad * 8 + kq * 32);
        }
        #pragma unroll
        for (int t = 0; t < NT; ++t) {
            bf16x8 b = *(const bf16x8*)(Wt + (t * 16 + m) * 128 + kq * 32 + quad * 8);
            acc[t] = __builtin_amdgcn_mfma_f32_16x16x32_bf16(a, b, acc[t], 0, 0, 0);
        }
    }

    // ---- h store ----
    #pragma unroll
    for (int r = 0; r < 4; ++r) {
        int node = n0 + quad * 4 + r;
        if (node < NN) {
            #pragma unroll
            for (int t = 0; t < NT; ++t)
                hout[(long long)node * COLS + t * 16 + m] =
                    (unsigned short)bf16rne(acc[t][r]);
        }
    }

    // ---- fused alpha: per-head dots + 16-lane reduction ----
    float asv[NT], adv[NT];
    #pragma unroll
    for (int t = 0; t < NT; ++t) { asv[t] = a_s[t * 16 + m]; adv[t] = a_d[t * 16 + m]; }

    #pragma unroll
    for (int r = 0; r < 4; ++r) {
        const int node = n0 + quad * 4 + r;
        #pragma unroll
        for (int hh = 0; hh < NH; ++hh) {
            float ps = 0.f, pd = 0.f;
            #pragma unroll
            for (int q = 0; q < TPH; ++q) {
                int t = hh * TPH + q;
                ps = fmaf(acc[t][r], asv[t], ps);
                pd = fmaf(acc[t][r], adv[t], pd);
            }
            #pragma unroll
            for (int off = 8; off > 0; off >>= 1) {
                ps += __shfl_down(ps, off, 16);
                pd += __shfl_down(pd, off, 16);
            }
            if (m == 0 && node < NN) {
                asrc[node * NH + hh] = ps;
                adst[node * NH + hh] = pd;
            }
        }
    }

    // sentinel row for masked-tail aggregation: exp(-1e30 + ...) == 0
    if (blockIdx.x == 0 && threadIdx.x == 0) {
        #pragma unroll
        for (int hh = 0; hh < NH; ++hh) asrc[NN * NH + hh] = -1e30f;
    }
}

// ---------------------------------------------------------------------------
// CSR build (2 kernels). pairs is SEGMENTED: bucket b owns
// pairs[b*CAP .. b*CAP+cnt_b). bucket_bin reserves space via atomicAdd on
// zero-initialized bcursor (final value = exact bucket count); bucket_sort
// computes the global CSR base by scanning the 256 counts in LDS.
// Record packing: src:16 | dlocal:8 | bucket:8.
// ---------------------------------------------------------------------------
__global__ __launch_bounds__(256) void bucket_bin(
    const int* __restrict__ ei, int* __restrict__ bcursor,
    unsigned* __restrict__ pairs)
{
    __shared__ int cnt[NBUCK];
    __shared__ int scanex[NBUCK];
    __shared__ int base[NBUCK];
    __shared__ int cur[NBUCK];
    __shared__ unsigned stage[CH];       // 16 KB

    const int tid = threadIdx.x;
    const long long e0 = (long long)blockIdx.x * CH;
    cnt[tid] = 0;
    __syncthreads();

    unsigned rec[EPT]; int bk[EPT];
    #pragma unroll
    for (int j = 0; j < EPT; ++j) {
        long long e = e0 + tid + j * 256;
        bool valid = e < E2C;
        int ss = 0, dd = 0;
        if (valid) {
            if (e < EE) { ss = ei[e]; dd = ei[EE + e]; }
            else        { ss = dd = (int)(e - EE); }
        }
        int b = dd / BW;
        bk[j]  = valid ? b : -1;
        rec[j] = (unsigned)ss | ((unsigned)(dd - b * BW) << 16) | ((unsigned)b << 24);
        if (valid) atomicAdd(&cnt[b], 1);
    }
    __syncthreads();

    const int myc = cnt[tid];
    scanex[tid] = myc;
    __syncthreads();
    for (int off = 1; off < NBUCK; off <<= 1) {
        int t = (tid >= off) ? scanex[tid - off] : 0;
        __syncthreads();
        scanex[tid] += t;
        __syncthreads();
    }
    int excl = scanex[tid] - myc;
    __syncthreads();
    scanex[tid] = excl;
    cur[tid]    = excl;
    base[tid]   = atomicAdd(&bcursor[tid], myc);   // reserve chunk in segment
    __syncthreads();

    #pragma unroll
    for (int j = 0; j < EPT; ++j) {
        if (bk[j] >= 0) {
            int p = atomicAdd(&cur[bk[j]], 1);
            stage[p] = rec[j];
        }
    }
    __syncthreads();

    const int total = (e0 + CH <= E2C) ? CH : (int)(E2C - e0);
    for (int j = tid; j < total; j += 256) {
        unsigned p = stage[j];
        int b = (int)(p >> 24);
        pairs[(size_t)b * CAP + base[b] + (j - scanex[b])] = p;
    }
}

__global__ __launch_bounds__(256) void bucket_sort(
    const int* __restrict__ bcursor, const unsigned* __restrict__ pairs,
    int* __restrict__ rowptr, unsigned short* __restrict__ sorted_src)
{
    __shared__ int deg[256];
    __shared__ int cur[256];
    __shared__ int gsc[256];
    const int b  = blockIdx.x;
    const int n0 = b * BW;
    const int n1 = (n0 + BW < NN) ? n0 + BW : NN;
    const int nloc = n1 - n0;
    const int tid = threadIdx.x;

    // global exclusive scan of bucket counts -> this bucket's CSR base
    int cb = bcursor[tid];
    gsc[tid] = cb;
    __syncthreads();
    for (int off = 1; off < NBUCK; off <<= 1) {
        int t = (tid >= off) ? gsc[tid - off] : 0;
        __syncthreads();
        gsc[tid] += t;
        __syncthreads();
    }
    const int mycnt = bcursor[b];
    const int beg   = gsc[b] - mycnt;      // exclusive prefix for bucket b
    const unsigned* seg = pairs + (size_t)b * CAP;

    deg[tid] = 0;
    __syncthreads();
    for (int i = tid; i < mycnt; i += 256)
        atomicAdd(&deg[(seg[i] >> 16) & 0xff], 1);
    __syncthreads();

    int v = deg[tid];
    cur[tid] = v;
    __syncthreads();
    for (int off = 1; off < 256; off <<= 1) {
        int t = (tid >= off) ? cur[tid - off] : 0;
        __syncthreads();
        cur[tid] += t;
        __syncthreads();
    }
    int excl = cur[tid] - v;
    __syncthreads();
    cur[tid] = beg + excl;
    if (tid < nloc) rowptr[n0 + tid] = beg + excl;
    if (b == NBUCK - 1 && tid == 0) rowptr[NN] = E2C;
    __syncthreads();

    for (int i = tid; i < mycnt; i += 256) {
        unsigned p = seg[i];
        int pos = atomicAdd(&cur[(p >> 16) & 0xff], 1);
        sorted_src[pos] = (unsigned short)(p & 0xffff);
    }
}

// ---------------------------------------------------------------------------
// CSR gather aggregation over bf16 h (round-12, unchanged): consecutive-d,
// 4-deep masked batches with sentinel node NN (asrc=-1e30 => zero weight).
// ---------------------------------------------------------------------------
template<int COLS, int NH, bool DO_ELU, bool OUTBF>
__global__ __launch_bounds__(256) void aggr_csr(
    const int* __restrict__ rowptr, const unsigned short* __restrict__ sorted_src,
    const unsigned short* __restrict__ hin,
    const float* __restrict__ asrc, const float* __restrict__ adst,
    const float* __restrict__ bias, void* __restrict__ outv)
{
    constexpr int TPN = COLS / 8;             // lanes per node: 16 or 4
    constexpr int USTR = COLS / 2;            // uints per h row
    int t = blockIdx.x * 256 + threadIdx.x;
    int d = t / TPN;
    int lc = t % TPN;                         // owns channels 8*lc .. 8*lc+7
    if (d >= NN) return;
    const int cc = lc * 8;
    const int head = cc / 32;                 // 0..NH-1
    const float ad = adst[d * NH + head];
    const int beg = rowptr[d], end = rowptr[d + 1];
    const uint* hp = (const uint*)hin + cc / 2;

    float num[8] = {};
    float den = 0.f;

    for (int i = beg; i < end; i += 4) {
        int   s[4];
        float a[4];
        uint4 Hv[4];
        #pragma unroll
        for (int j = 0; j < 4; ++j) {
            int sv = sorted_src[i + j];               // +3 over-read: slack alloc
            s[j] = (i + j < end) ? sv : NN;           // sentinel
        }
        #pragma unroll
        for (int j = 0; j < 4; ++j) a[j] = asrc[s[j] * NH + head];
        #pragma unroll
        for (int j = 0; j < 4; ++j)
            Hv[j] = *(const uint4*)&hp[(long long)s[j] * USTR];
        #pragma unroll
        for (int j = 0; j < 4; ++j) {
            float l = a[j] + ad; l = l > 0.f ? l : 0.2f * l;
            float w = __builtin_expf(l);
            den += w;
            num[0] = fmaf(w, bflo(Hv[j].x), num[0]); num[1] = fmaf(w, bfhi(Hv[j].x), num[1]);
            num[2] = fmaf(w, bflo(Hv[j].y), num[2]); num[3] = fmaf(w, bfhi(Hv[j].y), num[3]);
            num[4] = fmaf(w, bflo(Hv[j].z), num[4]); num[5] = fmaf(w, bfhi(Hv[j].z), num[5]);
            num[6] = fmaf(w, bflo(Hv[j].w), num[6]); num[7] = fmaf(w, bfhi(Hv[j].w), num[7]);
        }
    }

    float inv = 1.f / (den + 1e-16f);
    float v[8];
    #pragma unroll
    for (int j = 0; j < 8; ++j) {
        v[j] = num[j] * inv + bias[cc + j];
        if (DO_ELU) v[j] = v[j] > 0.f ? v[j] : expm1f(v[j]);
    }
    if constexpr (OUTBF) {
        uint4 u;
        u.x = bf16rne(v[0]) | (bf16rne(v[1]) << 16);
        u.y = bf16rne(v[2]) | (bf16rne(v[3]) << 16);
        u.z = bf16rne(v[4]) | (bf16rne(v[5]) << 16);
        u.w = bf16rne(v[6]) | (bf16rne(v[7]) << 16);
        *(uint4*)((unsigned short*)outv + (long long)d * COLS + cc) = u;
    } else {
        float4 o0 = {v[0], v[1], v[2], v[3]};
        float4 o1 = {v[4], v[5], v[6], v[7]};
        float* out = (float*)outv;
        *(float4*)&out[(long long)d * COLS + cc]     = o0;
        *(float4*)&out[(long long)d * COLS + cc + 4] = o1;
    }
}

// ---------------------------------------------------------------------------
extern "C" void kernel_launch(void* const* d_in, const int* in_sizes, int n_in,
                              void* d_out, int out_size, void* d_ws, size_t ws_size,
                              hipStream_t stream)
{
    const float* x   = (const float*)d_in[0];
    const int*   ei  = (const int*)  d_in[1];
    const float* W1  = (const float*)d_in[2];
    const float* as1 = (const float*)d_in[3];
    const float* ad1 = (const float*)d_in[4];
    const float* b1  = (const float*)d_in[5];
    const float* W2  = (const float*)d_in[6];
    const float* as2 = (const float*)d_in[7];
    const float* ad2 = (const float*)d_in[8];
    const float* b2  = (const float*)d_in[9];
    const float* W3  = (const float*)d_in[10];
    const float* as3 = (const float*)d_in[11];
    const float* ad3 = (const float*)d_in[12];
    const float* b3  = (const float*)d_in[13];
    float* out = (float*)d_out;

    // workspace layout (16B-aligned bf16 buffers first). h has sentinel row.
    unsigned short* H16 = (unsigned short*)d_ws;          // (N+1)*128 bf16
    unsigned short* O16 = H16 + (size_t)(NN + 1) * 128;   // N*128 bf16
    unsigned short* P16 = O16 + (size_t)NN * 128;         // N*128 bf16
    unsigned short* W1t = P16 + (size_t)NN * 128;         // 128*128 bf16
    unsigned short* W2t = W1t + 128 * 128;
    unsigned short* W3t = W2t + 128 * 128;                // 32*128
    float* ASRC = (float*)(W3t + 32 * 128);               // (N+1)*4
    float* ADST = ASRC + (size_t)(NN + 1) * 4;            // N*4
    int* rowptr = (int*)(ADST + (size_t)NN * 4);          // NN+1
    unsigned short* sorted = (unsigned short*)(rowptr + NN + 1);   // E2C+8 u16
    int* bcursor = (int*)(sorted + E2C + 8);              // NBUCK
    size_t off = ((size_t)(bcursor + NBUCK) - (size_t)d_ws + 15) & ~(size_t)15;
    unsigned* pairs = (unsigned*)((char*)d_ws + off);     // NBUCK*CAP u32 (4 MB)

    const int gCvtW    = (4608 + 255) / 256;             // 18
    const int gGemm    = (NN + 63) / 64;                 // 782
    const int gAggr128 = (NN * 16 + 255) / 256;          // 3125
    const int gAggr32  = (NN * 4 + 255) / 256;           // 782

    // ---- CSR build (reused by all layers) + weight conversion ----
    hipMemsetAsync(bcursor, 0, NBUCK * sizeof(int), stream);
    bucket_bin<<<NB_B, 256, 0, stream>>>(ei, bcursor, pairs);
    bucket_sort<<<NBUCK, 256, 0, stream>>>(bcursor, pairs, rowptr, sorted);
    cvt_weights<<<gCvtW, 256, 0, stream>>>(W1, W2, W3, W1t, W2t, W3t);

    // ---- layer 1 (128 -> 4x32 concat, ELU); fp32 x read directly ----
    gemm_mfma<8, 4, true><<<gGemm, 256, 0, stream>>>(x, W1t, as1, ad1, H16, ASRC, ADST);
    aggr_csr<128, 4, true, true><<<gAggr128, 256, 0, stream>>>(
        rowptr, sorted, H16, ASRC, ADST, b1, O16);

    // ---- layer 2 (128 -> 4x32 concat, ELU) ----
    gemm_mfma<8, 4, false><<<gGemm, 256, 0, stream>>>(O16, W2t, as2, ad2, H16, ASRC, ADST);
    aggr_csr<128, 4, true, true><<<gAggr128, 256, 0, stream>>>(
        rowptr, sorted, H16, ASRC, ADST, b2, P16);

    // ---- layer 3 (128 -> 32, 1 head, no concat) ----
    gemm_mfma<2, 1, false><<<gGemm, 256, 0, stream>>>(P16, W3t, as3, ad3, H16, ASRC, ADST);
    aggr_csr<32, 1, false, false><<<gAggr32, 256, 0, stream>>>(
        rowptr, sorted, H16, ASRC, ADST, b3, out);
}

// Round 14
// 276.996 us; speedup vs baseline: 1.1513x; 1.0530x over previous
//
#include <hip/hip_runtime.h>
#include <cmath>

constexpr int NN  = 50000;          // nodes
constexpr int EE  = 800000;         // raw edges
constexpr int E2C = EE + NN;        // edges incl. self loops = 850000
constexpr int DIM = 128;            // input dim to every layer's GEMM

// bucketed counting sort params
constexpr int NBUCK = 256;          // dst buckets
constexpr int BW    = 196;          // bucket width: 196*256 = 50176 >= NN
constexpr int EPT   = 16;           // edges per thread (bin)
constexpr int CH    = 256 * EPT;    // 4096 edges per block
constexpr int NB_B  = (E2C + CH - 1) / CH;  // 208 blocks
constexpr int CAP   = 4096;         // per-bucket pairs capacity (mean 3332, +13 sigma)
constexpr int SCAP  = 5120;         // per-bucket padded sorted capacity (mean ~3630)

using bf16x8 = __attribute__((ext_vector_type(8))) short;
using f32x4  = __attribute__((ext_vector_type(4))) float;

// bf16 helpers (storage bf16, math fp32)
__device__ inline unsigned bf16rne(float f) {
    unsigned u = __builtin_bit_cast(unsigned, f);
    return (u + 0x7fffu + ((u >> 16) & 1u)) >> 16;     // round-nearest-even
}
__device__ inline float bflo(unsigned u) { return __builtin_bit_cast(float, u << 16); }
__device__ inline float bfhi(unsigned u) { return __builtin_bit_cast(float, u & 0xffff0000u); }

// ---------------------------------------------------------------------------
// W[k,c] fp32 -> Wt[c,k] bf16, all three weights in one kernel.
// ---------------------------------------------------------------------------
__global__ __launch_bounds__(256) void cvt_weights(
    const float* __restrict__ W1, const float* __restrict__ W2,
    const float* __restrict__ W3,
    unsigned short* __restrict__ W1t, unsigned short* __restrict__ W2t,
    unsigned short* __restrict__ W3t)
{
    int g = blockIdx.x * 256 + threadIdx.x;
    const float* W; unsigned short* Wt; int cols;
    if (g < 2048)      { W = W1; Wt = W1t; cols = 128; }
    else if (g < 4096) { W = W2; Wt = W2t; cols = 128; g -= 2048; }
    else if (g < 4608) { W = W3; Wt = W3t; cols = 32;  g -= 4096; }
    else return;
    int c  = g / 16;
    int k8 = (g % 16) * 8;
    unsigned up[4];
    #pragma unroll
    for (int j = 0; j < 4; ++j) {
        float a = W[(k8 + 2 * j) * cols + c];
        float b = W[(k8 + 2 * j + 1) * cols + c];
        up[j] = bf16rne(a) | (bf16rne(b) << 16);
    }
    uint4 u; u.x = up[0]; u.y = up[1]; u.z = up[2]; u.w = up[3];
    *(uint4*)(Wt + c * 128 + k8) = u;
}

// ---------------------------------------------------------------------------
// MFMA GEMM + fused attention coefficients (round-12, unchanged).
// ---------------------------------------------------------------------------
template<int NT, int NH, bool F32IN>
__global__ __launch_bounds__(256) void gemm_mfma(
    const void* __restrict__ inv, const unsigned short* __restrict__ Wt,
    const float* __restrict__ a_s, const float* __restrict__ a_d,
    unsigned short* __restrict__ hout, float* __restrict__ asrc,
    float* __restrict__ adst)
{
    constexpr int COLS = NT * 16;
    constexpr int TPH  = NT / NH;        // tiles per head (2)
    const int lane = threadIdx.x & 63;
    const int wave = threadIdx.x >> 6;
    const int m    = lane & 15;
    const int quad = lane >> 4;
    const int n0   = blockIdx.x * 64 + wave * 16;

    int arow = n0 + m; if (arow >= NN) arow = NN - 1;

    f32x4 acc[NT] = {};
    #pragma unroll
    for (int kq = 0; kq < 4; ++kq) {
        bf16x8 a;
        if constexpr (F32IN) {
            const float* ap = (const float*)inv + (long long)arow * 128 + quad * 8 + kq * 32;
            float4 v0 = *(const float4*)ap;
            float4 v1 = *(const float4*)(ap + 4);
            a[0] = (short)bf16rne(v0.x); a[1] = (short)bf16rne(v0.y);
            a[2] = (short)bf16rne(v0.z); a[3] = (short)bf16rne(v0.w);
            a[4] = (short)bf16rne(v1.x); a[5] = (short)bf16rne(v1.y);
            a[6] = (short)bf16rne(v1.z); a[7] = (short)bf16rne(v1.w);
        } else {
            a = *(const bf16x8*)((const unsigned short*)inv
                    + (long long)arow * 128 + quad * 8 + kq * 32);
        }
        #pragma unroll
        for (int t = 0; t < NT; ++t) {
            bf16x8 b = *(const bf16x8*)(Wt + (t * 16 + m) * 128 + kq * 32 + quad * 8);
            acc[t] = __builtin_amdgcn_mfma_f32_16x16x32_bf16(a, b, acc[t], 0, 0, 0);
        }
    }

    // ---- h store ----
    #pragma unroll
    for (int r = 0; r < 4; ++r) {
        int node = n0 + quad * 4 + r;
        if (node < NN) {
            #pragma unroll
            for (int t = 0; t < NT; ++t)
                hout[(long long)node * COLS + t * 16 + m] =
                    (unsigned short)bf16rne(acc[t][r]);
        }
    }

    // ---- fused alpha: per-head dots + 16-lane reduction ----
    float asv[NT], adv[NT];
    #pragma unroll
    for (int t = 0; t < NT; ++t) { asv[t] = a_s[t * 16 + m]; adv[t] = a_d[t * 16 + m]; }

    #pragma unroll
    for (int r = 0; r < 4; ++r) {
        const int node = n0 + quad * 4 + r;
        #pragma unroll
        for (int hh = 0; hh < NH; ++hh) {
            float ps = 0.f, pd = 0.f;
            #pragma unroll
            for (int q = 0; q < TPH; ++q) {
                int t = hh * TPH + q;
                ps = fmaf(acc[t][r], asv[t], ps);
                pd = fmaf(acc[t][r], adv[t], pd);
            }
            #pragma unroll
            for (int off = 8; off > 0; off >>= 1) {
                ps += __shfl_down(ps, off, 16);
                pd += __shfl_down(pd, off, 16);
            }
            if (m == 0 && node < NN) {
                asrc[node * NH + hh] = ps;
                adst[node * NH + hh] = pd;
            }
        }
    }

    // sentinel row: pads in sorted point to node NN -> exp(-1e30) == 0
    if (blockIdx.x == 0 && threadIdx.x == 0) {
        #pragma unroll
        for (int hh = 0; hh < NH; ++hh) asrc[NN * NH + hh] = -1e30f;
    }
}

// ---------------------------------------------------------------------------
// CSR build (2 kernels). pairs segmented per bucket (CAP each); sorted is
// segmented per bucket (SCAP each) with every node's range padded to a
// multiple of 4; pad slots hold sentinel node NN. Per-node range stored as
// int2 (beg, end). Record packing: src:16 | dlocal:8 | bucket:8.
// ---------------------------------------------------------------------------
__global__ __launch_bounds__(256) void bucket_bin(
    const int* __restrict__ ei, int* __restrict__ bcursor,
    unsigned* __restrict__ pairs)
{
    __shared__ int cnt[NBUCK];
    __shared__ int scanex[NBUCK];
    __shared__ int base[NBUCK];
    __shared__ int cur[NBUCK];
    __shared__ unsigned stage[CH];       // 16 KB

    const int tid = threadIdx.x;
    const long long e0 = (long long)blockIdx.x * CH;
    cnt[tid] = 0;
    __syncthreads();

    unsigned rec[EPT]; int bk[EPT];
    #pragma unroll
    for (int j = 0; j < EPT; ++j) {
        long long e = e0 + tid + j * 256;
        bool valid = e < E2C;
        int ss = 0, dd = 0;
        if (valid) {
            if (e < EE) { ss = ei[e]; dd = ei[EE + e]; }
            else        { ss = dd = (int)(e - EE); }
        }
        int b = dd / BW;
        bk[j]  = valid ? b : -1;
        rec[j] = (unsigned)ss | ((unsigned)(dd - b * BW) << 16) | ((unsigned)b << 24);
        if (valid) atomicAdd(&cnt[b], 1);
    }
    __syncthreads();

    const int myc = cnt[tid];
    scanex[tid] = myc;
    __syncthreads();
    for (int off = 1; off < NBUCK; off <<= 1) {
        int t = (tid >= off) ? scanex[tid - off] : 0;
        __syncthreads();
        scanex[tid] += t;
        __syncthreads();
    }
    int excl = scanex[tid] - myc;
    __syncthreads();
    scanex[tid] = excl;
    cur[tid]    = excl;
    base[tid]   = atomicAdd(&bcursor[tid], myc);   // reserve chunk in segment
    __syncthreads();

    #pragma unroll
    for (int j = 0; j < EPT; ++j) {
        if (bk[j] >= 0) {
            int p = atomicAdd(&cur[bk[j]], 1);
            stage[p] = rec[j];
        }
    }
    __syncthreads();

    const int total = (e0 + CH <= E2C) ? CH : (int)(E2C - e0);
    for (int j = tid; j < total; j += 256) {
        unsigned p = stage[j];
        int b = (int)(p >> 24);
        pairs[(size_t)b * CAP + base[b] + (j - scanex[b])] = p;
    }
}

__global__ __launch_bounds__(256) void bucket_sort(
    const int* __restrict__ bcursor, const unsigned* __restrict__ pairs,
    int2* __restrict__ rowp, unsigned short* __restrict__ sorted_src)
{
    __shared__ int deg[256];
    __shared__ int scn[256];
    __shared__ int cur[256];
    const int b  = blockIdx.x;
    const int n0 = b * BW;
    const int n1 = (n0 + BW < NN) ? n0 + BW : NN;
    const int nloc = n1 - n0;
    const int tid = threadIdx.x;
    const int mycnt = bcursor[b];
    const unsigned* seg = pairs + (size_t)b * CAP;
    const int base = b * SCAP;

    deg[tid] = 0;
    __syncthreads();
    for (int i = tid; i < mycnt; i += 256)
        atomicAdd(&deg[(seg[i] >> 16) & 0xff], 1);
    __syncthreads();

    const int pv = (deg[tid] + 3) & ~3;            // degree padded to mult of 4
    scn[tid] = pv;
    __syncthreads();
    for (int off = 1; off < 256; off <<= 1) {
        int t = (tid >= off) ? scn[tid - off] : 0;
        __syncthreads();
        scn[tid] += t;
        __syncthreads();
    }
    const int totalp = scn[255];
    const int pexcl  = scn[tid] - pv;
    cur[tid] = base + pexcl;
    if (tid < nloc) rowp[n0 + tid] = make_int2(base + pexcl, base + pexcl + pv);
    __syncthreads();

    // sentinel-fill padded extent, then scatter real entries over it
    for (int i = tid; i < totalp; i += 256)
        sorted_src[base + i] = (unsigned short)NN;
    __syncthreads();
    for (int i = tid; i < mycnt; i += 256) {
        unsigned p = seg[i];
        int pos = atomicAdd(&cur[(p >> 16) & 0xff], 1);
        sorted_src[pos] = (unsigned short)(p & 0xffff);
    }
}

// ---------------------------------------------------------------------------
// CSR gather aggregation over bf16 h: padded mask-free 4-deep batches.
// One aligned ushort4 index load per batch, prefetched one batch ahead;
// pads are sentinel node NN (w = 0). 8 channels/lane, COLS/8 lanes/node.
// ---------------------------------------------------------------------------
template<int COLS, int NH, bool DO_ELU, bool OUTBF>
__global__ __launch_bounds__(256) void aggr_csr(
    const int2* __restrict__ rowp, const unsigned short* __restrict__ sorted_src,
    const unsigned short* __restrict__ hin,
    const float* __restrict__ asrc, const float* __restrict__ adst,
    const float* __restrict__ bias, void* __restrict__ outv)
{
    constexpr int TPN = COLS / 8;             // lanes per node: 16 or 4
    constexpr int USTR = COLS / 2;            // uints per h row
    int t = blockIdx.x * 256 + threadIdx.x;
    int d = t / TPN;
    int lc = t % TPN;                         // owns channels 8*lc .. 8*lc+7
    if (d >= NN) return;
    const int cc = lc * 8;
    const int head = cc / 32;                 // 0..NH-1
    const float ad = adst[d * NH + head];
    const int2 be = rowp[d];
    const int beg = be.x, end = be.y;         // 4-aligned; deg >= 1 => beg < end
    const uint* hp = (const uint*)hin + cc / 2;

    float num[8] = {};
    float den = 0.f;

    ushort4 sv = *(const ushort4*)&sorted_src[beg];
    for (int i = beg; i < end; i += 4) {
        ushort4 nx = *(const ushort4*)&sorted_src[i + 4];   // segment slack
        const int s[4] = {sv.x, sv.y, sv.z, sv.w};
        float a[4];
        uint4 Hv[4];
        #pragma unroll
        for (int j = 0; j < 4; ++j) a[j] = asrc[s[j] * NH + head];
        #pragma unroll
        for (int j = 0; j < 4; ++j)
            Hv[j] = *(const uint4*)&hp[(long long)s[j] * USTR];
        #pragma unroll
        for (int j = 0; j < 4; ++j) {
            float l = a[j] + ad; l = l > 0.f ? l : 0.2f * l;
            float w = __builtin_expf(l);
            den += w;
            num[0] = fmaf(w, bflo(Hv[j].x), num[0]); num[1] = fmaf(w, bfhi(Hv[j].x), num[1]);
            num[2] = fmaf(w, bflo(Hv[j].y), num[2]); num[3] = fmaf(w, bfhi(Hv[j].y), num[3]);
            num[4] = fmaf(w, bflo(Hv[j].z), num[4]); num[5] = fmaf(w, bfhi(Hv[j].z), num[5]);
            num[6] = fmaf(w, bflo(Hv[j].w), num[6]); num[7] = fmaf(w, bfhi(Hv[j].w), num[7]);
        }
        sv = nx;
    }

    float inv = 1.f / (den + 1e-16f);
    float v[8];
    #pragma unroll
    for (int j = 0; j < 8; ++j) {
        v[j] = num[j] * inv + bias[cc + j];
        if (DO_ELU) v[j] = v[j] > 0.f ? v[j] : expm1f(v[j]);
    }
    if constexpr (OUTBF) {
        uint4 u;
        u.x = bf16rne(v[0]) | (bf16rne(v[1]) << 16);
        u.y = bf16rne(v[2]) | (bf16rne(v[3]) << 16);
        u.z = bf16rne(v[4]) | (bf16rne(v[5]) << 16);
        u.w = bf16rne(v[6]) | (bf16rne(v[7]) << 16);
        *(uint4*)((unsigned short*)outv + (long long)d * COLS + cc) = u;
    } else {
        float4 o0 = {v[0], v[1], v[2], v[3]};
        float4 o1 = {v[4], v[5], v[6], v[7]};
        float* out = (float*)outv;
        *(float4*)&out[(long long)d * COLS + cc]     = o0;
        *(float4*)&out[(long long)d * COLS + cc + 4] = o1;
    }
}

// ---------------------------------------------------------------------------
extern "C" void kernel_launch(void* const* d_in, const int* in_sizes, int n_in,
                              void* d_out, int out_size, void* d_ws, size_t ws_size,
                              hipStream_t stream)
{
    const float* x   = (const float*)d_in[0];
    const int*   ei  = (const int*)  d_in[1];
    const float* W1  = (const float*)d_in[2];
    const float* as1 = (const float*)d_in[3];
    const float* ad1 = (const float*)d_in[4];
    const float* b1  = (const float*)d_in[5];
    const float* W2  = (const float*)d_in[6];
    const float* as2 = (const float*)d_in[7];
    const float* ad2 = (const float*)d_in[8];
    const float* b2  = (const float*)d_in[9];
    const float* W3  = (const float*)d_in[10];
    const float* as3 = (const float*)d_in[11];
    const float* ad3 = (const float*)d_in[12];
    const float* b3  = (const float*)d_in[13];
    float* out = (float*)d_out;

    // workspace layout (16B-aligned bf16 buffers first). H16 has sentinel row.
    unsigned short* H16 = (unsigned short*)d_ws;          // (N+1)*128 bf16
    unsigned short* O16 = H16 + (size_t)(NN + 1) * 128;   // N*128 bf16
    unsigned short* P16 = O16 + (size_t)NN * 128;         // N*128 bf16
    unsigned short* W1t = P16 + (size_t)NN * 128;         // 128*128 bf16
    unsigned short* W2t = W1t + 128 * 128;
    unsigned short* W3t = W2t + 128 * 128;                // 32*128
    float* ASRC = (float*)(W3t + 32 * 128);               // (N+1)*4
    float* ADST = ASRC + (size_t)(NN + 1) * 4;            // N*4
    int2* rowp  = (int2*)(ADST + (size_t)NN * 4);         // NN int2
    unsigned short* sorted = (unsigned short*)(rowp + NN);         // NBUCK*SCAP+8 u16
    int* bcursor = (int*)(sorted + (size_t)NBUCK * SCAP + 8);      // NBUCK
    size_t off = ((size_t)(bcursor + NBUCK) - (size_t)d_ws + 15) & ~(size_t)15;
    unsigned* pairs = (unsigned*)((char*)d_ws + off);     // NBUCK*CAP u32 (4 MB)

    const int gCvtW    = (4608 + 255) / 256;             // 18
    const int gGemm    = (NN + 63) / 64;                 // 782
    const int gAggr128 = (NN * 16 + 255) / 256;          // 3125
    const int gAggr32  = (NN * 4 + 255) / 256;           // 782

    // ---- CSR build (reused by all layers) + weight conversion ----
    hipMemsetAsync(bcursor, 0, NBUCK * sizeof(int), stream);
    bucket_bin<<<NB_B, 256, 0, stream>>>(ei, bcursor, pairs);
    bucket_sort<<<NBUCK, 256, 0, stream>>>(bcursor, pairs, rowp, sorted);
    cvt_weights<<<gCvtW, 256, 0, stream>>>(W1, W2, W3, W1t, W2t, W3t);

    // ---- layer 1 (128 -> 4x32 concat, ELU); fp32 x read directly ----
    gemm_mfma<8, 4, true><<<gGemm, 256, 0, stream>>>(x, W1t, as1, ad1, H16, ASRC, ADST);
    aggr_csr<128, 4, true, true><<<gAggr128, 256, 0, stream>>>(
        rowp, sorted, H16, ASRC, ADST, b1, O16);

    // ---- layer 2 (128 -> 4x32 concat, ELU) ----
    gemm_mfma<8, 4, false><<<gGemm, 256, 0, stream>>>(O16, W2t, as2, ad2, H16, ASRC, ADST);
    aggr_csr<128, 4, true, true><<<gAggr128, 256, 0, stream>>>(
        rowp, sorted, H16, ASRC, ADST, b2, P16);

    // ---- layer 3 (128 -> 32, 1 head, no concat) ----
    gemm_mfma<2, 1, false><<<gGemm, 256, 0, stream>>>(P16, W3t, as3, ad3, H16, ASRC, ADST);
    aggr_csr<32, 1, false, false><<<gAggr32, 256, 0, stream>>>(
        rowp, sorted, H16, ASRC, ADST, b3, out);
}